// Round 14
// baseline (145.430 us; speedup 1.0000x reference)
//
#include <hip/hip_runtime.h>

typedef unsigned short u16;
typedef __attribute__((ext_vector_type(4))) float f32x4;
typedef __attribute__((ext_vector_type(8))) short bf16x8;

#define AS1 __attribute__((address_space(1)))
#define AS3 __attribute__((address_space(3)))

__device__ __forceinline__ float bf2f(u16 u) {
  union { unsigned int i; float f; } v; v.i = ((unsigned int)u) << 16; return v.f;
}
__device__ __forceinline__ u16 f2bf(float f) {
  union { float f; unsigned int i; } v; v.f = f;
  unsigned int r = v.i + 0x7fffu + ((v.i >> 16) & 1u);  // RNE
  return (u16)(r >> 16);
}
__device__ __forceinline__ void gload16(const void* g, void* l) {
  __builtin_amdgcn_global_load_lds((const AS1 unsigned int*)g, (AS3 unsigned int*)l, 16, 0, 0);
}

struct GemmDesc {
  const u16* A;      // [M][K] bf16, row stride lda
  const u16* Bt;     // [N][K] bf16, row stride ldb (B transposed)
  u16* D;            // optional bf16 out, row stride ldd
  u16* Dt;           // optional bf16 transposed out [N][M], row stride lddt
  float* Df;         // optional f32 out, row stride ldd
  int M, N, K, lda, ldb, ldd, lddt, tn, tiles;
  float scale;
};
struct GemmBatch { GemmDesc d[4]; int nd; };

template<int BM, int BN, int FM, int FN>
__device__ __forceinline__ void epilogue(const GemmDesc& d, f32x4 (&acc)[FM][FN],
                                         int m0, int n0, int wm, int wn, int lane) {
  const int r4 = (lane >> 4) << 2;
  const int cc = lane & 15;
  #pragma unroll
  for (int i = 0; i < FM; ++i) {
    #pragma unroll
    for (int j = 0; j < FN; ++j) {
      const int row0 = m0 + wm * (BM / 2) + i * 16 + r4;
      const int col = n0 + wn * (BN / 2) + j * 16 + cc;
      float v[4];
      #pragma unroll
      for (int q = 0; q < 4; ++q) v[q] = acc[i][j][q];
      if (d.scale != 1.0f) {
        #pragma unroll
        for (int q = 0; q < 4; ++q) v[q] *= d.scale;
      }
      if (d.D) {
        #pragma unroll
        for (int q = 0; q < 4; ++q) d.D[(size_t)(row0 + q) * d.ldd + col] = f2bf(v[q]);
      }
      if (d.Df) {
        #pragma unroll
        for (int q = 0; q < 4; ++q) d.Df[(size_t)(row0 + q) * d.ldd + col] = v[q];
      }
      if (d.Dt) {
        ushort4 pk = make_ushort4(f2bf(v[0]), f2bf(v[1]), f2bf(v[2]), f2bf(v[3]));
        *(ushort4*)&d.Dt[(size_t)col * d.lddt + row0] = pk;
      }
    }
  }
}

// ---------- 2-buffer double-buffered pipelined kernel, T2 XOR-swizzled LDS ----------
// Exactly the R8-proven schedule: counted vmcnt, raw barriers, loads in flight
// across barriers. 64 KB LDS at 128x128 -> 2 blocks/CU capacity.
template<int BM, int BN>
__global__ __launch_bounds__(256) void gemm_db(GemmBatch b) {
  const int nwg = gridDim.x;  // multiple of 8
  int t = ((blockIdx.x & 7) * (nwg >> 3)) + (blockIdx.x >> 3);
  int di = 0;
  while (di + 1 < b.nd && t >= b.d[di].tiles) { t -= b.d[di].tiles; ++di; }
  const GemmDesc d = b.d[di];
  const int tm = t / d.tn, tnn = t - tm * d.tn;
  const int m0 = tm * BM, n0 = tnn * BN;
  const int lane = threadIdx.x & 63;
  const int w = threadIdx.x >> 6;
  const int wm = w >> 1, wn = w & 1;
  constexpr int FM = BM / 32, FN = BN / 32;
  constexpr int HB = (BM + BN) * 64;       // u16 elems per half
  constexpr int L = (BM + BN) / 32;        // gload16 per wave per tile
  __shared__ __align__(16) u16 lds[2 * HB];
  f32x4 acc[FM][FN];
  #pragma unroll
  for (int i = 0; i < FM; ++i)
    #pragma unroll
    for (int j = 0; j < FN; ++j)
      acc[i][j] = (f32x4){0.f, 0.f, 0.f, 0.f};
  const int srow = lane >> 3;
  const int scolz = (((lane & 7) << 3) ^ (srow << 3));  // pre-swizzled source col
  const int rsw = (lane & 7) << 3;                      // read-side XOR constant
  const int nt = d.K / 64;

  auto stagef = [&](int tt, int half) {
    const int k0 = tt * 64;
    u16* base = &lds[half * HB];
    #pragma unroll
    for (int c = w; c < BM / 8; c += 4)
      gload16(d.A + (size_t)(m0 + c * 8 + srow) * d.lda + k0 + scolz, base + c * 512);
    #pragma unroll
    for (int c = w; c < BN / 8; c += 4)
      gload16(d.Bt + (size_t)(n0 + c * 8 + srow) * d.ldb + k0 + scolz, base + BM * 64 + c * 512);
  };

  // prologue: 2-deep prefetch (K >= 128 in all uses)
  stagef(0, 0);
  stagef(1, 1);
  __builtin_amdgcn_sched_barrier(0);
  asm volatile("s_waitcnt vmcnt(%0)" :: "n"(L));  // tile0 landed (ours)
  __builtin_amdgcn_s_barrier();                   // everyone's tile0 landed
  __builtin_amdgcn_sched_barrier(0);

  for (int tt = 0; tt < nt; ++tt) {
    const u16* base = &lds[(tt & 1) * HB];
    #pragma unroll
    for (int kk = 0; kk < 64; kk += 32) {
      const int cb = (kk + ((lane >> 4) << 3)) ^ rsw;  // swizzled col base
      bf16x8 af[FM], bfr[FN];
      #pragma unroll
      for (int i = 0; i < FM; ++i)
        af[i] = *(const bf16x8*)&base[(wm * (BM / 2) + i * 16 + (lane & 15)) * 64 + cb];
      #pragma unroll
      for (int j = 0; j < FN; ++j)
        bfr[j] = *(const bf16x8*)&base[BM * 64 + (wn * (BN / 2) + j * 16 + (lane & 15)) * 64 + cb];
      #pragma unroll
      for (int i = 0; i < FM; ++i)
        #pragma unroll
        for (int j = 0; j < FN; ++j)
          acc[i][j] = __builtin_amdgcn_mfma_f32_16x16x32_bf16(af[i], bfr[j], acc[i][j], 0, 0, 0);
    }
    if (tt + 1 < nt) {
      __builtin_amdgcn_s_barrier();      // all waves done reading buf[tt&1]
      __builtin_amdgcn_sched_barrier(0);
      if (tt + 2 < nt) {
        stagef(tt + 2, tt & 1);          // refill freed buffer; loads fly across barrier
        __builtin_amdgcn_sched_barrier(0);
        asm volatile("s_waitcnt vmcnt(%0)" :: "n"(L));  // tile tt+1 landed; tt+2 in flight
      } else {
        asm volatile("s_waitcnt vmcnt(0)");
      }
      __builtin_amdgcn_s_barrier();      // everyone's tile tt+1 landed
      __builtin_amdgcn_sched_barrier(0);
    }
  }
  epilogue<BM, BN, FM, FN>(d, acc, m0, n0, wm, wn, lane);
}

// ---------- one fused conversion kernel: 2688 units, grid 1344 x2 ----------
__global__ __launch_bounds__(256) void conv_all(const float* Af, const float* AFf,
                                                const float* Cf, const float* BFf,
                                                const float* CFf,
                                                u16* Mb, u16* Nb, u16* NbT, u16* Cb,
                                                u16* KP, u16* BFT, u16* CFb) {
  __shared__ float tile[64][65];
  const int tid = threadIdx.x;
  const int lr = tid >> 6, lc = tid & 63;
  for (int u = blockIdx.x; u < 2688; u += 1344) {
    __syncthreads();
    if (u < 1024) {              // Mb = A^T
      int tr = u >> 5, tc = u & 31;
      int r0 = tr << 6, c0 = tc << 6;
      #pragma unroll
      for (int p = 0; p < 16; ++p) {
        int r = p * 4 + lr;
        tile[r][lc] = Af[(size_t)(r0 + r) * 2048 + c0 + lc];
      }
      __syncthreads();
      #pragma unroll
      for (int p = 0; p < 16; ++p) {
        int r = p * 4 + lr;
        Mb[(size_t)(c0 + r) * 2048 + r0 + lc] = f2bf(tile[lc][r]);
      }
    } else if (u < 2048) {       // Nb = A_F straight ; NbT = A_F^T
      int bb = u - 1024;
      int tr = bb >> 5, tc = bb & 31;
      int r0 = tr << 6, c0 = tc << 6;
      #pragma unroll
      for (int p = 0; p < 16; ++p) {
        int r = p * 4 + lr;
        float v = AFf[(size_t)(r0 + r) * 2048 + c0 + lc];
        tile[r][lc] = v;
        Nb[(size_t)(r0 + r) * 2048 + c0 + lc] = f2bf(v);
      }
      __syncthreads();
      #pragma unroll
      for (int p = 0; p < 16; ++p) {
        int r = p * 4 + lr;
        NbT[(size_t)(c0 + r) * 2048 + r0 + lc] = f2bf(tile[lc][r]);
      }
    } else if (u < 2304) {       // Cb = C straight ; KP cols 0-511 = C^T
      int bb = u - 2048;
      int tr = bb >> 5, tc = bb & 31;
      int r0 = tr << 6, c0 = tc << 6;
      #pragma unroll
      for (int p = 0; p < 16; ++p) {
        int r = p * 4 + lr;
        float v = Cf[(size_t)(r0 + r) * 2048 + c0 + lc];
        tile[r][lc] = v;
        Cb[(size_t)(r0 + r) * 2048 + c0 + lc] = f2bf(v);
      }
      __syncthreads();
      #pragma unroll
      for (int p = 0; p < 16; ++p) {
        int r = p * 4 + lr;
        KP[(size_t)(c0 + r) * 2048 + r0 + lc] = f2bf(tile[lc][r]);
      }
    } else if (u < 2560) {       // BFT = B_F^T
      int bb = u - 2304;
      int tr = bb >> 3, tc = bb & 7;
      int r0 = tr << 6, c0 = tc << 6;
      #pragma unroll
      for (int p = 0; p < 16; ++p) {
        int r = p * 4 + lr;
        tile[r][lc] = BFf[(size_t)(r0 + r) * 512 + c0 + lc];
      }
      __syncthreads();
      #pragma unroll
      for (int p = 0; p < 16; ++p) {
        int r = p * 4 + lr;
        BFT[(size_t)(c0 + r) * 2048 + r0 + lc] = f2bf(tile[lc][r]);
      }
    } else {                     // CFb = C_F straight (128 stride-units)
      const int n4 = (512 * 2048) / 4;
      for (int i = (u - 2560) * 256 + tid; i < n4; i += 128 * 256) {
        float4 f = ((const float4*)CFf)[i];
        ((ushort4*)CFb)[i] = make_ushort4(f2bf(f.x), f2bf(f.y), f2bf(f.z), f2bf(f.w));
      }
    }
  }
}

// t[row] = sum_j KP[row][j], KP bf16 [n][width]; grid = n/4 blocks
__global__ __launch_bounds__(256) void rowsum_bf(const u16* KP, float* t, int width) {
  int w = threadIdx.x >> 6, lane = threadIdx.x & 63;
  int row = blockIdx.x * 4 + w;
  float s = 0.f;
  for (int k0 = lane * 8; k0 < width; k0 += 512) {
    bf16x8 mv = *(const bf16x8*)&KP[(size_t)row * width + k0];
    #pragma unroll
    for (int e = 0; e < 8; ++e) s += bf2f((u16)mv[e]);
  }
  #pragma unroll
  for (int off = 32; off > 0; off >>= 1) s += __shfl_down(s, off);
  if (lane == 0) t[row] = s;
}

// fused: u[row] = dot(C_row, t); D_hat[row][:] = 0.5*(1-u)/512 + 0.5*DF[row][:]
__global__ __launch_bounds__(256) void matvec_dhat(const float* Cm, const float* t,
                                                   const float* DF, float* out) {
  __shared__ float ts[2048];
  for (int i = threadIdx.x; i < 2048; i += 256) ts[i] = t[i];
  __syncthreads();
  int w = threadIdx.x >> 6, lane = threadIdx.x & 63;
  int row = blockIdx.x * 4 + w;
  float s = 0.f;
  for (int k0 = lane * 4; k0 < 2048; k0 += 256) {
    float4 c4 = *(const float4*)&Cm[(size_t)row * 2048 + k0];
    s += c4.x * ts[k0] + c4.y * ts[k0 + 1] + c4.z * ts[k0 + 2] + c4.w * ts[k0 + 3];
  }
  #pragma unroll
  for (int off = 32; off > 0; off >>= 1) s += __shfl_down(s, off);
  s = __shfl(s, 0);
  float coef = 0.5f * (1.0f - s) * (1.0f / 512.0f);
  int j = lane * 8;
  #pragma unroll
  for (int e = 0; e < 8; ++e)
    out[(size_t)row * 512 + j + e] = coef + 0.5f * DF[(size_t)row * 512 + j + e];
}

extern "C" void kernel_launch(void* const* d_in, const int* in_sizes, int n_in,
                              void* d_out, int out_size, void* d_ws, size_t ws_size,
                              hipStream_t stream) {
  (void)in_sizes; (void)n_in; (void)out_size; (void)ws_size;
  const float* Cf  = (const float*)d_in[0];  // [512][2048]
  const float* Af  = (const float*)d_in[1];  // [2048][2048]
  const float* AFf = (const float*)d_in[2];  // [2048][2048]
  const float* BFf = (const float*)d_in[3];  // [2048][512]
  const float* CFf = (const float*)d_in[4];  // [512][2048]
  const float* DFf = (const float*)d_in[5];  // [512][512]
  float* out = (float*)d_out;                // B_hat [2048][512] ++ D_hat [512][512]

  const size_t NN = 2048ull * 2048ull;
  const size_t SK = 512ull * 2048ull;
  char* ws = (char*)d_ws;
  u16* Mb   = (u16*)ws;            // M = A^T [2048][2048]
  u16* Nb   = Mb + NN;             // N = A_F [2048][2048]
  u16* NbT  = Nb + NN;             // N^T [2048][2048]
  u16* KP   = NbT + NN;            // [P0|P1|P2|P3] [2048][2048]
  u16* Cb   = KP + NN;             // C [512][2048] (= P0^T)
  u16* P1T  = Cb + SK;             // P1^T
  u16* P2T  = P1T + SK;            // P2^T
  u16* BFT  = P2T + SK;            // B_F^T = e0^T
  u16* E1T  = BFT + SK;            // e1^T
  u16* E2T  = E1T + SK;            // e2^T
  u16* R1   = E2T + SK;            // r1 = C_F N  [512][2048] straight
  u16* WB   = R1 + SK;             // [w0^T|w1^T|w2^T|w3^T] [512][2048]
  u16* CFb  = WB + SK;             // C_F [512][2048]
  float* tv = (float*)(CFb + SK);  // t [2048]

  auto mk = [](const u16* A, int lda, const u16* Bt, int ldb,
               u16* D, u16* Dt, float* Df, int ldd, int lddt,
               int M, int N, int K, float scale, int bm, int bn) {
    GemmDesc g; g.A = A; g.Bt = Bt; g.D = D; g.Dt = Dt; g.Df = Df;
    g.M = M; g.N = N; g.K = K; g.lda = lda; g.ldb = ldb; g.ldd = ldd; g.lddt = lddt;
    g.tn = N / bn; g.tiles = (M / bm) * (N / bn); g.scale = scale; return g;
  };

  // ---- all conversions in one launch ----
  conv_all<<<1344, 256, 0, stream>>>(Af, AFf, Cf, BFf, CFf, Mb, Nb, NbT, Cb, KP, BFT, CFb);

  // ---- GA (208): P1 = M@P0 (D->KP+512, Dt->P1T) | e1 = N@e0 (Dt->E1T) | r1 = C_F@N (D->R1) | w0 = C_F@e0 (Dt->WB) ----
  { GemmBatch gb{}; gb.nd = 4;
    gb.d[0] = mk(Mb, 2048, Cb, 2048, KP + 512, P1T, nullptr, 2048, 2048, 2048, 512, 2048, 1.f, 128, 128);
    gb.d[1] = mk(Nb, 2048, BFT, 2048, nullptr, E1T, nullptr, 0, 2048, 2048, 512, 2048, 1.f, 128, 128);
    gb.d[2] = mk(CFb, 2048, NbT, 2048, R1, nullptr, nullptr, 2048, 0, 512, 2048, 2048, 1.f, 128, 128);
    gb.d[3] = mk(CFb, 2048, BFT, 2048, nullptr, WB, nullptr, 0, 2048, 512, 512, 2048, 1.f, 128, 128);
    gemm_db<128, 128><<<208, 256, 0, stream>>>(gb); }

  // ---- GB (160): P2 = M@P1 (D->KP+1024, Dt->P2T) | e2 = N@e1 (Dt->E2T) | w1 = C_F@e1 | w2 = r1@e1 ----
  { GemmBatch gb{}; gb.nd = 4;
    gb.d[0] = mk(Mb, 2048, P1T, 2048, KP + 1024, P2T, nullptr, 2048, 2048, 2048, 512, 2048, 1.f, 128, 128);
    gb.d[1] = mk(Nb, 2048, E1T, 2048, nullptr, E2T, nullptr, 0, 2048, 2048, 512, 2048, 1.f, 128, 128);
    gb.d[2] = mk(CFb, 2048, E1T, 2048, nullptr, WB + 512, nullptr, 0, 2048, 512, 512, 2048, 1.f, 128, 128);
    gb.d[3] = mk(R1, 2048, E1T, 2048, nullptr, WB + 1024, nullptr, 0, 2048, 512, 512, 2048, 1.f, 128, 128);
    gemm_db<128, 128><<<160, 256, 0, stream>>>(gb); }

  // ---- GC (80): P3 = M@P2 (D->KP+1536) | w3 = r1@e2 ----
  { GemmBatch gb{}; gb.nd = 2;
    gb.d[0] = mk(Mb, 2048, P2T, 2048, KP + 1536, nullptr, nullptr, 2048, 0, 2048, 512, 2048, 1.f, 128, 128);
    gb.d[1] = mk(R1, 2048, E2T, 2048, nullptr, WB + 1536, nullptr, 0, 2048, 512, 512, 2048, 1.f, 128, 128);
    gemm_db<128, 128><<<80, 256, 0, stream>>>(gb); }

  // ---- GD (64): B_hat = -(KP @ WB^T) -> d_out f32, K=2048 ----
  { GemmBatch gb{}; gb.nd = 1;
    gb.d[0] = mk(KP, 2048, WB, 2048, nullptr, nullptr, out, 512, 0, 2048, 512, 2048, -1.f, 128, 128);
    gemm_db<128, 128><<<64, 256, 0, stream>>>(gb); }

  // ---- D_hat: t = rowsum(KP) ; u = C t ; D_hat fused ----
  rowsum_bf<<<512, 256, 0, stream>>>(KP, tv, 2048);
  matvec_dhat<<<128, 256, 0, stream>>>(Cf, tv, DFf, out + 2048 * 512);
}

// Round 15
// 117.642 us; speedup vs baseline: 1.2362x; 1.2362x over previous
//
#include <hip/hip_runtime.h>

typedef unsigned short u16;
typedef __attribute__((ext_vector_type(4))) float f32x4;
typedef __attribute__((ext_vector_type(8))) short bf16x8;

#define AS1 __attribute__((address_space(1)))
#define AS3 __attribute__((address_space(3)))

__device__ __forceinline__ float bf2f(u16 u) {
  union { unsigned int i; float f; } v; v.i = ((unsigned int)u) << 16; return v.f;
}
__device__ __forceinline__ u16 f2bf(float f) {
  union { float f; unsigned int i; } v; v.f = f;
  unsigned int r = v.i + 0x7fffu + ((v.i >> 16) & 1u);  // RNE
  return (u16)(r >> 16);
}
__device__ __forceinline__ void gload16(const void* g, void* l) {
  __builtin_amdgcn_global_load_lds((const AS1 unsigned int*)g, (AS3 unsigned int*)l, 16, 0, 0);
}

struct GemmDesc {
  const u16* A;      // [M][K] bf16, row stride lda
  const u16* Bt;     // [N][K] bf16, row stride ldb (B transposed)
  u16* D;            // optional bf16 out, row stride ldd
  u16* Dt;           // optional bf16 transposed out [N][M], row stride lddt
  float* Df;         // optional f32 out, row stride ldd
  int M, N, K, lda, ldb, ldd, lddt, tn, tiles;
  float scale;
};
struct GemmBatch { GemmDesc d[8]; int nd; };

template<int BM, int BN, int FM, int FN>
__device__ __forceinline__ void epilogue(const GemmDesc& d, f32x4 (&acc)[FM][FN],
                                         int m0, int n0, int wm, int wn, int lane) {
  const int r4 = (lane >> 4) << 2;
  const int cc = lane & 15;
  #pragma unroll
  for (int i = 0; i < FM; ++i) {
    #pragma unroll
    for (int j = 0; j < FN; ++j) {
      const int row0 = m0 + wm * (BM / 2) + i * 16 + r4;
      const int col = n0 + wn * (BN / 2) + j * 16 + cc;
      float v[4];
      #pragma unroll
      for (int q = 0; q < 4; ++q) v[q] = acc[i][j][q];
      if (d.scale != 1.0f) {
        #pragma unroll
        for (int q = 0; q < 4; ++q) v[q] *= d.scale;
      }
      if (d.D) {
        #pragma unroll
        for (int q = 0; q < 4; ++q) d.D[(size_t)(row0 + q) * d.ldd + col] = f2bf(v[q]);
      }
      if (d.Df) {
        #pragma unroll
        for (int q = 0; q < 4; ++q) d.Df[(size_t)(row0 + q) * d.ldd + col] = v[q];
      }
      if (d.Dt) {
        ushort4 pk = make_ushort4(f2bf(v[0]), f2bf(v[1]), f2bf(v[2]), f2bf(v[3]));
        *(ushort4*)&d.Dt[(size_t)col * d.lddt + row0] = pk;
      }
    }
  }
}

// ---------- BK=128 double-buffered pipelined kernel, T2 XOR-swizzled LDS ----------
// Each buffer = two linear 64-col sub-tiles (gload_lds needs linear dests).
// One barrier pair per 128-K step (half the sync overhead of BK=64).
// LDS[r][c] within a half holds global[r][c ^ ((r&7)<<3)].
template<int BM, int BN>
__global__ __launch_bounds__(256) void gemm_db(GemmBatch b) {
  const int nwg = gridDim.x;  // multiple of 8
  int t = ((blockIdx.x & 7) * (nwg >> 3)) + (blockIdx.x >> 3);
  int di = 0;
  while (di + 1 < b.nd && t >= b.d[di].tiles) { t -= b.d[di].tiles; ++di; }
  const GemmDesc d = b.d[di];
  const int tm = t / d.tn, tnn = t - tm * d.tn;
  const int m0 = tm * BM, n0 = tnn * BN;
  const int lane = threadIdx.x & 63;
  const int w = threadIdx.x >> 6;
  const int wm = w >> 1, wn = w & 1;
  constexpr int FM = BM / 32, FN = BN / 32;
  constexpr int HB = (BM + BN) * 64;       // u16 per 64-col half
  constexpr int L = 2 * (BM + BN) / 32;    // gload16 per wave per 128-K tile
  __shared__ __align__(16) u16 lds[4 * HB];  // 2 buffers x 2 halves
  f32x4 acc[FM][FN];
  #pragma unroll
  for (int i = 0; i < FM; ++i)
    #pragma unroll
    for (int j = 0; j < FN; ++j)
      acc[i][j] = (f32x4){0.f, 0.f, 0.f, 0.f};
  const int srow = lane >> 3;
  const int scolz = (((lane & 7) << 3) ^ (srow << 3));  // pre-swizzled source col
  const int rsw = (lane & 7) << 3;                      // read-side XOR constant
  const int nt = d.K / 128;                             // >= 2 in all uses

  auto stagef = [&](int tt, int buf) {
    #pragma unroll
    for (int h = 0; h < 2; ++h) {
      const int k0 = tt * 128 + h * 64;
      u16* base = &lds[(buf * 2 + h) * HB];
      #pragma unroll
      for (int c = w; c < BM / 8; c += 4)
        gload16(d.A + (size_t)(m0 + c * 8 + srow) * d.lda + k0 + scolz, base + c * 512);
      #pragma unroll
      for (int c = w; c < BN / 8; c += 4)
        gload16(d.Bt + (size_t)(n0 + c * 8 + srow) * d.ldb + k0 + scolz, base + BM * 64 + c * 512);
    }
  };

  // prologue: 2-deep prefetch
  stagef(0, 0);
  stagef(1, 1);
  __builtin_amdgcn_sched_barrier(0);
  asm volatile("s_waitcnt vmcnt(%0)" :: "n"(L));  // tile0 landed (ours)
  __builtin_amdgcn_s_barrier();                   // everyone's tile0 landed
  __builtin_amdgcn_sched_barrier(0);

  for (int tt = 0; tt < nt; ++tt) {
    #pragma unroll
    for (int h = 0; h < 2; ++h) {
      const u16* base = &lds[((tt & 1) * 2 + h) * HB];
      #pragma unroll
      for (int kk = 0; kk < 64; kk += 32) {
        const int cb = (kk + ((lane >> 4) << 3)) ^ rsw;  // swizzled col base
        bf16x8 af[FM], bfr[FN];
        #pragma unroll
        for (int i = 0; i < FM; ++i)
          af[i] = *(const bf16x8*)&base[(wm * (BM / 2) + i * 16 + (lane & 15)) * 64 + cb];
        #pragma unroll
        for (int j = 0; j < FN; ++j)
          bfr[j] = *(const bf16x8*)&base[BM * 64 + (wn * (BN / 2) + j * 16 + (lane & 15)) * 64 + cb];
        #pragma unroll
        for (int i = 0; i < FM; ++i)
          #pragma unroll
          for (int j = 0; j < FN; ++j)
            acc[i][j] = __builtin_amdgcn_mfma_f32_16x16x32_bf16(af[i], bfr[j], acc[i][j], 0, 0, 0);
      }
    }
    if (tt + 1 < nt) {
      __builtin_amdgcn_s_barrier();      // all waves done reading buf[tt&1]
      __builtin_amdgcn_sched_barrier(0);
      if (tt + 2 < nt) {
        stagef(tt + 2, tt & 1);          // refill freed buffer; loads fly across barrier
        __builtin_amdgcn_sched_barrier(0);
        asm volatile("s_waitcnt vmcnt(%0)" :: "n"(L));  // tile tt+1 landed; tt+2 in flight
      } else {
        asm volatile("s_waitcnt vmcnt(0)");
      }
      __builtin_amdgcn_s_barrier();      // everyone's tile tt+1 landed
      __builtin_amdgcn_sched_barrier(0);
    }
  }
  epilogue<BM, BN, FM, FN>(d, acc, m0, n0, wm, wn, lane);
}

// ---------- one fused conversion kernel ----------
__global__ __launch_bounds__(256) void conv_all(const float* Af, const float* AFf,
                                                const float* Cf, const float* BFf,
                                                const float* CFf,
                                                u16* Mb, u16* Nb, u16* NbT, u16* Cb,
                                                u16* KP, u16* BFT, u16* CFb) {
  __shared__ float tile[64][65];
  const int tid = threadIdx.x;
  const int lr = tid >> 6, lc = tid & 63;
  for (int u = blockIdx.x; u < 2688; u += 1344) {
    __syncthreads();
    if (u < 1024) {              // Mb = A^T
      int tr = u >> 5, tc = u & 31;
      int r0 = tr << 6, c0 = tc << 6;
      #pragma unroll
      for (int p = 0; p < 16; ++p) {
        int r = p * 4 + lr;
        tile[r][lc] = Af[(size_t)(r0 + r) * 2048 + c0 + lc];
      }
      __syncthreads();
      #pragma unroll
      for (int p = 0; p < 16; ++p) {
        int r = p * 4 + lr;
        Mb[(size_t)(c0 + r) * 2048 + r0 + lc] = f2bf(tile[lc][r]);
      }
    } else if (u < 2048) {       // Nb = A_F straight ; NbT = A_F^T
      int bb = u - 1024;
      int tr = bb >> 5, tc = bb & 31;
      int r0 = tr << 6, c0 = tc << 6;
      #pragma unroll
      for (int p = 0; p < 16; ++p) {
        int r = p * 4 + lr;
        float v = AFf[(size_t)(r0 + r) * 2048 + c0 + lc];
        tile[r][lc] = v;
        Nb[(size_t)(r0 + r) * 2048 + c0 + lc] = f2bf(v);
      }
      __syncthreads();
      #pragma unroll
      for (int p = 0; p < 16; ++p) {
        int r = p * 4 + lr;
        NbT[(size_t)(c0 + r) * 2048 + r0 + lc] = f2bf(tile[lc][r]);
      }
    } else if (u < 2304) {       // Cb = C straight ; KP cols 0-511 = C^T
      int bb = u - 2048;
      int tr = bb >> 5, tc = bb & 31;
      int r0 = tr << 6, c0 = tc << 6;
      #pragma unroll
      for (int p = 0; p < 16; ++p) {
        int r = p * 4 + lr;
        float v = Cf[(size_t)(r0 + r) * 2048 + c0 + lc];
        tile[r][lc] = v;
        Cb[(size_t)(r0 + r) * 2048 + c0 + lc] = f2bf(v);
      }
      __syncthreads();
      #pragma unroll
      for (int p = 0; p < 16; ++p) {
        int r = p * 4 + lr;
        KP[(size_t)(c0 + r) * 2048 + r0 + lc] = f2bf(tile[lc][r]);
      }
    } else if (u < 2560) {       // BFT = B_F^T
      int bb = u - 2304;
      int tr = bb >> 3, tc = bb & 7;
      int r0 = tr << 6, c0 = tc << 6;
      #pragma unroll
      for (int p = 0; p < 16; ++p) {
        int r = p * 4 + lr;
        tile[r][lc] = BFf[(size_t)(r0 + r) * 512 + c0 + lc];
      }
      __syncthreads();
      #pragma unroll
      for (int p = 0; p < 16; ++p) {
        int r = p * 4 + lr;
        BFT[(size_t)(c0 + r) * 2048 + r0 + lc] = f2bf(tile[lc][r]);
      }
    } else {                     // CFb = C_F straight
      const int n4 = (512 * 2048) / 4;
      for (int i = (u - 2560) * 256 + tid; i < n4; i += 128 * 256) {
        float4 f = ((const float4*)CFf)[i];
        ((ushort4*)CFb)[i] = make_ushort4(f2bf(f.x), f2bf(f.y), f2bf(f.z), f2bf(f.w));
      }
    }
  }
}

// WB = WBp0 + WBp1 (bf16, n4 = elems/4)
__global__ __launch_bounds__(256) void comb_wb(const u16* a, const u16* b, u16* o, int n4) {
  int i = blockIdx.x * 256 + threadIdx.x;
  if (i >= n4) return;
  ushort4 x = ((const ushort4*)a)[i];
  ushort4 y = ((const ushort4*)b)[i];
  ushort4 r;
  r.x = f2bf(bf2f(x.x) + bf2f(y.x));
  r.y = f2bf(bf2f(x.y) + bf2f(y.y));
  r.z = f2bf(bf2f(x.z) + bf2f(y.z));
  r.w = f2bf(bf2f(x.w) + bf2f(y.w));
  ((ushort4*)o)[i] = r;
}

// out = -(a + b) (f32, n4 = elems/4)
__global__ __launch_bounds__(256) void comb_out(const float* a, const float* b, float* o, int n4) {
  int i = blockIdx.x * 256 + threadIdx.x;
  if (i >= n4) return;
  float4 x = ((const float4*)a)[i];
  float4 y = ((const float4*)b)[i];
  ((float4*)o)[i] = make_float4(-(x.x + y.x), -(x.y + y.y), -(x.z + y.z), -(x.w + y.w));
}

// t[row] = sum_j KP[row][j]
__global__ __launch_bounds__(256) void rowsum_bf(const u16* KP, float* t, int width) {
  int w = threadIdx.x >> 6, lane = threadIdx.x & 63;
  int row = blockIdx.x * 4 + w;
  float s = 0.f;
  for (int k0 = lane * 8; k0 < width; k0 += 512) {
    bf16x8 mv = *(const bf16x8*)&KP[(size_t)row * width + k0];
    #pragma unroll
    for (int e = 0; e < 8; ++e) s += bf2f((u16)mv[e]);
  }
  #pragma unroll
  for (int off = 32; off > 0; off >>= 1) s += __shfl_down(s, off);
  if (lane == 0) t[row] = s;
}

// fused: u[row] = dot(C_row, t); D_hat[row][:] = 0.5*(1-u)/512 + 0.5*DF[row][:]
__global__ __launch_bounds__(256) void matvec_dhat(const float* Cm, const float* t,
                                                   const float* DF, float* out) {
  __shared__ float ts[2048];
  for (int i = threadIdx.x; i < 2048; i += 256) ts[i] = t[i];
  __syncthreads();
  int w = threadIdx.x >> 6, lane = threadIdx.x & 63;
  int row = blockIdx.x * 4 + w;
  float s = 0.f;
  for (int k0 = lane * 4; k0 < 2048; k0 += 256) {
    float4 c4 = *(const float4*)&Cm[(size_t)row * 2048 + k0];
    s += c4.x * ts[k0] + c4.y * ts[k0 + 1] + c4.z * ts[k0 + 2] + c4.w * ts[k0 + 3];
  }
  #pragma unroll
  for (int off = 32; off > 0; off >>= 1) s += __shfl_down(s, off);
  s = __shfl(s, 0);
  float coef = 0.5f * (1.0f - s) * (1.0f / 512.0f);
  int j = lane * 8;
  #pragma unroll
  for (int e = 0; e < 8; ++e)
    out[(size_t)row * 512 + j + e] = coef + 0.5f * DF[(size_t)row * 512 + j + e];
}

extern "C" void kernel_launch(void* const* d_in, const int* in_sizes, int n_in,
                              void* d_out, int out_size, void* d_ws, size_t ws_size,
                              hipStream_t stream) {
  (void)in_sizes; (void)n_in; (void)out_size; (void)ws_size;
  const float* Cf  = (const float*)d_in[0];  // [512][2048]
  const float* Af  = (const float*)d_in[1];  // [2048][2048]
  const float* AFf = (const float*)d_in[2];  // [2048][2048]
  const float* BFf = (const float*)d_in[3];  // [2048][512]
  const float* CFf = (const float*)d_in[4];  // [512][2048]
  const float* DFf = (const float*)d_in[5];  // [512][512]
  float* out = (float*)d_out;                // B_hat [2048][512] ++ D_hat [512][512]

  const size_t NN = 2048ull * 2048ull;
  const size_t SK = 512ull * 2048ull;
  char* ws = (char*)d_ws;
  u16* Mb   = (u16*)ws;            // M = A^T [2048][2048]
  u16* Nb   = Mb + NN;             // N = A_F [2048][2048]
  u16* NbT  = Nb + NN;             // N^T
  u16* KP   = NbT + NN;            // [P0|P1|P2|P3] [2048][2048]
  u16* Cb   = KP + NN;             // C [512][2048] (= P0^T)
  u16* P1T  = Cb + SK;             // P1^T
  u16* P2T  = P1T + SK;            // P2^T
  u16* BFT  = P2T + SK;            // B_F^T = e0^T
  u16* E1T  = BFT + SK;            // e1^T
  u16* E2T  = E1T + SK;            // e2^T
  u16* R1   = E2T + SK;            // r1 = C_F N [512][2048]
  u16* WB   = R1 + SK;             // [w0^T|w1^T|w2^T|w3^T] [512][2048]
  u16* WBp0 = WB + SK;             // split-K partials
  u16* WBp1 = WBp0 + SK;
  u16* CFb  = WBp1 + SK;           // C_F [512][2048]
  float* Vp0 = (float*)(CFb + SK); // G5 partial f32 [2048][512]
  float* Vp1 = Vp0 + 2048ull * 512;
  float* tv  = Vp1 + 2048ull * 512;

  auto mk = [](const u16* A, int lda, const u16* Bt, int ldb,
               u16* D, u16* Dt, float* Df, int ldd, int lddt,
               int M, int N, int K, float scale, int bm, int bn) {
    GemmDesc g; g.A = A; g.Bt = Bt; g.D = D; g.Dt = Dt; g.Df = Df;
    g.M = M; g.N = N; g.K = K; g.lda = lda; g.ldb = ldb; g.ldd = ldd; g.lddt = lddt;
    g.tn = N / bn; g.tiles = (M / bm) * (N / bn); g.scale = scale; return g;
  };

  // ---- conversions ----
  conv_all<<<1344, 256, 0, stream>>>(Af, AFf, Cf, BFf, CFf, Mb, Nb, NbT, Cb, KP, BFT, CFb);

  // ---- G1 (256): P1 = M@P0 (D->KP+512, Dt->P1T) | e1 = N@e0 (Dt->E1T) ----
  { GemmBatch gb{}; gb.nd = 2;
    gb.d[0] = mk(Mb, 2048, Cb, 2048, KP + 512, P1T, nullptr, 2048, 2048, 2048, 512, 2048, 1.f, 128, 64);
    gb.d[1] = mk(Nb, 2048, BFT, 2048, nullptr, E1T, nullptr, 0, 2048, 2048, 512, 2048, 1.f, 128, 64);
    gemm_db<128, 64><<<256, 256, 0, stream>>>(gb); }

  // ---- G2 (256): P2 = M@P1 (D->KP+1024, Dt->P2T) | r1 = C_F@N (D->R1) ----
  { GemmBatch gb{}; gb.nd = 2;
    gb.d[0] = mk(Mb, 2048, P1T, 2048, KP + 1024, P2T, nullptr, 2048, 2048, 2048, 512, 2048, 1.f, 128, 64);
    gb.d[1] = mk(CFb, 2048, NbT, 2048, R1, nullptr, nullptr, 2048, 0, 512, 2048, 2048, 1.f, 128, 64);
    gemm_db<128, 64><<<256, 256, 0, stream>>>(gb); }

  // ---- G3 (256): P3 = M@P2 (D->KP+1536) | e2 = N@e1 (Dt->E2T) ----
  { GemmBatch gb{}; gb.nd = 2;
    gb.d[0] = mk(Mb, 2048, P2T, 2048, KP + 1536, nullptr, nullptr, 2048, 0, 2048, 512, 2048, 1.f, 128, 64);
    gb.d[1] = mk(Nb, 2048, E1T, 2048, nullptr, E2T, nullptr, 0, 2048, 2048, 512, 2048, 1.f, 128, 64);
    gemm_db<128, 64><<<256, 256, 0, stream>>>(gb); }

  // ---- G4 (256): w_k split-K=2 -> bf16 partials; w0,w1 = C_F@{e0,e1}; w2,w3 = r1@{e1,e2} ----
  { GemmBatch gb{}; gb.nd = 8;
    const u16* As[4] = {CFb, CFb, R1, R1};
    const u16* Bs[4] = {BFT, E1T, E1T, E2T};
    for (int k = 0; k < 4; ++k)
      for (int h = 0; h < 2; ++h)
        gb.d[k * 2 + h] = mk(As[k] + h * 1024, 2048, Bs[k] + h * 1024, 2048,
                             nullptr, (h ? WBp1 : WBp0) + 512 * k, nullptr, 0, 2048,
                             512, 512, 1024, 1.f, 128, 64);
    gemm_db<128, 64><<<256, 256, 0, stream>>>(gb); }
  comb_wb<<<1024, 256, 0, stream>>>(WBp0, WBp1, WB, (512 * 2048) / 4);

  // ---- G5 (256): B_hat split-K=2: Vp_h = KP[:,h*1024:]@WB[:,h*1024:]^T (f32) ----
  { GemmBatch gb{}; gb.nd = 2;
    gb.d[0] = mk(KP, 2048, WB, 2048, nullptr, nullptr, Vp0, 512, 0, 2048, 512, 1024, 1.f, 128, 64);
    gb.d[1] = mk(KP + 1024, 2048, WB + 1024, 2048, nullptr, nullptr, Vp1, 512, 0, 2048, 512, 1024, 1.f, 128, 64);
    gemm_db<128, 64><<<256, 256, 0, stream>>>(gb); }
  comb_out<<<1024, 256, 0, stream>>>(Vp0, Vp1, out, (2048 * 512) / 4);

  // ---- D_hat: t = rowsum(KP) ; u = C t ; D_hat fused ----
  rowsum_bf<<<512, 256, 0, stream>>>(KP, tv, 2048);
  matvec_dhat<<<128, 256, 0, stream>>>(Cf, tv, DFf, out + 2048 * 512);
}

// Round 16
// 117.236 us; speedup vs baseline: 1.2405x; 1.0035x over previous
//
#include <hip/hip_runtime.h>

typedef unsigned short u16;
typedef __attribute__((ext_vector_type(4))) float f32x4;
typedef __attribute__((ext_vector_type(8))) short bf16x8;

#define AS1 __attribute__((address_space(1)))
#define AS3 __attribute__((address_space(3)))

__device__ __forceinline__ float bf2f(u16 u) {
  union { unsigned int i; float f; } v; v.i = ((unsigned int)u) << 16; return v.f;
}
__device__ __forceinline__ u16 f2bf(float f) {
  union { float f; unsigned int i; } v; v.f = f;
  unsigned int r = v.i + 0x7fffu + ((v.i >> 16) & 1u);  // RNE
  return (u16)(r >> 16);
}
__device__ __forceinline__ void gload16(const void* g, void* l) {
  __builtin_amdgcn_global_load_lds((const AS1 unsigned int*)g, (AS3 unsigned int*)l, 16, 0, 0);
}

struct GemmDesc {
  const u16* A;      // [M][K] bf16, row stride lda
  const u16* Bt;     // [N][K] bf16, row stride ldb (B transposed)
  u16* D;            // optional bf16 out, row stride ldd
  u16* Dt;           // optional bf16 transposed out [N][M], row stride lddt
  float* Df;         // optional f32 out, row stride ldd
  int M, N, K, lda, ldb, ldd, lddt, tn, tiles;
  float scale;
};
struct GemmBatch { GemmDesc d[8]; int nd; };

template<int BM, int BN, int FM, int FN>
__device__ __forceinline__ void epilogue(const GemmDesc& d, f32x4 (&acc)[FM][FN],
                                         int m0, int n0, int wm, int wn, int lane) {
  const int r4 = (lane >> 4) << 2;
  const int cc = lane & 15;
  #pragma unroll
  for (int i = 0; i < FM; ++i) {
    #pragma unroll
    for (int j = 0; j < FN; ++j) {
      const int row0 = m0 + wm * (BM / 2) + i * 16 + r4;
      const int col = n0 + wn * (BN / 2) + j * 16 + cc;
      float v[4];
      #pragma unroll
      for (int q = 0; q < 4; ++q) v[q] = acc[i][j][q];
      if (d.scale != 1.0f) {
        #pragma unroll
        for (int q = 0; q < 4; ++q) v[q] *= d.scale;
      }
      if (d.D) {
        #pragma unroll
        for (int q = 0; q < 4; ++q) d.D[(size_t)(row0 + q) * d.ldd + col] = f2bf(v[q]);
      }
      if (d.Df) {
        #pragma unroll
        for (int q = 0; q < 4; ++q) d.Df[(size_t)(row0 + q) * d.ldd + col] = v[q];
      }
      if (d.Dt) {
        ushort4 pk = make_ushort4(f2bf(v[0]), f2bf(v[1]), f2bf(v[2]), f2bf(v[3]));
        *(ushort4*)&d.Dt[(size_t)col * d.lddt + row0] = pk;
      }
    }
  }
}

// ---------- BK=128, 3-buffer, ONE-barrier-per-K-step pipeline, T2-swizzled ----------
// Buffer rotation: iter tt computes buf tt%3 and stages tile tt+2 into buf
// (tt+2)%3 — which was last read at iter tt-1, and the single barrier at the
// end of iter tt-1 already proves all waves are done with it. vmcnt ledger:
// after staging, outstanding <= 2L (tiles tt+1, tt+2); vmcnt(L) => tile tt+1
// landed; barrier publishes. LDS = 3 x 48 KB = 144 KB (1 block/CU, which is
// all these <=256-WG phases can have anyway).
template<int BM, int BN>
__global__ __launch_bounds__(256) void gemm_db(GemmBatch b) {
  const int nwg = gridDim.x;  // multiple of 8
  int t = ((blockIdx.x & 7) * (nwg >> 3)) + (blockIdx.x >> 3);
  int di = 0;
  while (di + 1 < b.nd && t >= b.d[di].tiles) { t -= b.d[di].tiles; ++di; }
  const GemmDesc d = b.d[di];
  const int tm = t / d.tn, tnn = t - tm * d.tn;
  const int m0 = tm * BM, n0 = tnn * BN;
  const int lane = threadIdx.x & 63;
  const int w = threadIdx.x >> 6;
  const int wm = w >> 1, wn = w & 1;
  constexpr int FM = BM / 32, FN = BN / 32;
  constexpr int HB = (BM + BN) * 64;       // u16 per 64-col half
  constexpr int L = 2 * (BM + BN) / 32;    // gload16 per wave per 128-K tile
  __shared__ __align__(16) u16 lds[6 * HB];  // 3 buffers x 2 halves
  f32x4 acc[FM][FN];
  #pragma unroll
  for (int i = 0; i < FM; ++i)
    #pragma unroll
    for (int j = 0; j < FN; ++j)
      acc[i][j] = (f32x4){0.f, 0.f, 0.f, 0.f};
  const int srow = lane >> 3;
  const int scolz = (((lane & 7) << 3) ^ (srow << 3));  // pre-swizzled source col
  const int rsw = (lane & 7) << 3;                      // read-side XOR constant
  const int nt = d.K / 128;                             // >= 8 in all uses

  auto stagef = [&](int tt, int buf) {
    #pragma unroll
    for (int h = 0; h < 2; ++h) {
      const int k0 = tt * 128 + h * 64;
      u16* base = &lds[(buf * 2 + h) * HB];
      #pragma unroll
      for (int c = w; c < BM / 8; c += 4)
        gload16(d.A + (size_t)(m0 + c * 8 + srow) * d.lda + k0 + scolz, base + c * 512);
      #pragma unroll
      for (int c = w; c < BN / 8; c += 4)
        gload16(d.Bt + (size_t)(n0 + c * 8 + srow) * d.ldb + k0 + scolz, base + BM * 64 + c * 512);
    }
  };

  // prologue: stage tiles 0,1 (tile 2 staged inside iter 0)
  stagef(0, 0);
  stagef(1, 1);
  __builtin_amdgcn_sched_barrier(0);
  asm volatile("s_waitcnt vmcnt(%0)" :: "n"(L));  // tile0 landed (ours); tile1 in flight
  __builtin_amdgcn_s_barrier();                   // everyone's tile0 landed
  __builtin_amdgcn_sched_barrier(0);

  int cur = 0;
  for (int tt = 0; tt < nt; ++tt) {
    #pragma unroll
    for (int h = 0; h < 2; ++h) {
      const u16* base = &lds[(cur * 2 + h) * HB];
      #pragma unroll
      for (int kk = 0; kk < 64; kk += 32) {
        const int cb = (kk + ((lane >> 4) << 3)) ^ rsw;  // swizzled col base
        bf16x8 af[FM], bfr[FN];
        #pragma unroll
        for (int i = 0; i < FM; ++i)
          af[i] = *(const bf16x8*)&base[(wm * (BM / 2) + i * 16 + (lane & 15)) * 64 + cb];
        #pragma unroll
        for (int j = 0; j < FN; ++j)
          bfr[j] = *(const bf16x8*)&base[BM * 64 + (wn * (BN / 2) + j * 16 + (lane & 15)) * 64 + cb];
        #pragma unroll
        for (int i = 0; i < FM; ++i)
          #pragma unroll
          for (int j = 0; j < FN; ++j)
            acc[i][j] = __builtin_amdgcn_mfma_f32_16x16x32_bf16(af[i], bfr[j], acc[i][j], 0, 0, 0);
      }
    }
    if (tt + 1 < nt) {
      __builtin_amdgcn_sched_barrier(0);
      if (tt + 2 < nt) {
        int nb = cur + 2; if (nb >= 3) nb -= 3;   // (tt+2)%3 — safe: read at iter tt-1
        stagef(tt + 2, nb);                       // loads fly across the barrier
        __builtin_amdgcn_sched_barrier(0);
        asm volatile("s_waitcnt vmcnt(%0)" :: "n"(L));  // tile tt+1 landed; tt+2 in flight
      } else {
        asm volatile("s_waitcnt vmcnt(0)");
      }
      __builtin_amdgcn_s_barrier();      // single barrier per K-step
      __builtin_amdgcn_sched_barrier(0);
    }
    cur = (cur == 2) ? 0 : cur + 1;
  }
  epilogue<BM, BN, FM, FN>(d, acc, m0, n0, wm, wn, lane);
}

// ---------- one fused conversion kernel ----------
__global__ __launch_bounds__(256) void conv_all(const float* Af, const float* AFf,
                                                const float* Cf, const float* BFf,
                                                const float* CFf,
                                                u16* Mb, u16* Nb, u16* NbT, u16* Cb,
                                                u16* KP, u16* BFT, u16* CFb) {
  __shared__ float tile[64][65];
  const int tid = threadIdx.x;
  const int lr = tid >> 6, lc = tid & 63;
  for (int u = blockIdx.x; u < 2688; u += 1344) {
    __syncthreads();
    if (u < 1024) {              // Mb = A^T
      int tr = u >> 5, tc = u & 31;
      int r0 = tr << 6, c0 = tc << 6;
      #pragma unroll
      for (int p = 0; p < 16; ++p) {
        int r = p * 4 + lr;
        tile[r][lc] = Af[(size_t)(r0 + r) * 2048 + c0 + lc];
      }
      __syncthreads();
      #pragma unroll
      for (int p = 0; p < 16; ++p) {
        int r = p * 4 + lr;
        Mb[(size_t)(c0 + r) * 2048 + r0 + lc] = f2bf(tile[lc][r]);
      }
    } else if (u < 2048) {       // Nb = A_F straight ; NbT = A_F^T
      int bb = u - 1024;
      int tr = bb >> 5, tc = bb & 31;
      int r0 = tr << 6, c0 = tc << 6;
      #pragma unroll
      for (int p = 0; p < 16; ++p) {
        int r = p * 4 + lr;
        float v = AFf[(size_t)(r0 + r) * 2048 + c0 + lc];
        tile[r][lc] = v;
        Nb[(size_t)(r0 + r) * 2048 + c0 + lc] = f2bf(v);
      }
      __syncthreads();
      #pragma unroll
      for (int p = 0; p < 16; ++p) {
        int r = p * 4 + lr;
        NbT[(size_t)(c0 + r) * 2048 + r0 + lc] = f2bf(tile[lc][r]);
      }
    } else if (u < 2304) {       // Cb = C straight ; KP cols 0-511 = C^T
      int bb = u - 2048;
      int tr = bb >> 5, tc = bb & 31;
      int r0 = tr << 6, c0 = tc << 6;
      #pragma unroll
      for (int p = 0; p < 16; ++p) {
        int r = p * 4 + lr;
        float v = Cf[(size_t)(r0 + r) * 2048 + c0 + lc];
        tile[r][lc] = v;
        Cb[(size_t)(r0 + r) * 2048 + c0 + lc] = f2bf(v);
      }
      __syncthreads();
      #pragma unroll
      for (int p = 0; p < 16; ++p) {
        int r = p * 4 + lr;
        KP[(size_t)(c0 + r) * 2048 + r0 + lc] = f2bf(tile[lc][r]);
      }
    } else if (u < 2560) {       // BFT = B_F^T
      int bb = u - 2304;
      int tr = bb >> 3, tc = bb & 7;
      int r0 = tr << 6, c0 = tc << 6;
      #pragma unroll
      for (int p = 0; p < 16; ++p) {
        int r = p * 4 + lr;
        tile[r][lc] = BFf[(size_t)(r0 + r) * 512 + c0 + lc];
      }
      __syncthreads();
      #pragma unroll
      for (int p = 0; p < 16; ++p) {
        int r = p * 4 + lr;
        BFT[(size_t)(c0 + r) * 2048 + r0 + lc] = f2bf(tile[lc][r]);
      }
    } else {                     // CFb = C_F straight
      const int n4 = (512 * 2048) / 4;
      for (int i = (u - 2560) * 256 + tid; i < n4; i += 128 * 256) {
        float4 f = ((const float4*)CFf)[i];
        ((ushort4*)CFb)[i] = make_ushort4(f2bf(f.x), f2bf(f.y), f2bf(f.z), f2bf(f.w));
      }
    }
  }
}

// WB = WBp0 + WBp1 (bf16, n4 = elems/4)
__global__ __launch_bounds__(256) void comb_wb(const u16* a, const u16* b, u16* o, int n4) {
  int i = blockIdx.x * 256 + threadIdx.x;
  if (i >= n4) return;
  ushort4 x = ((const ushort4*)a)[i];
  ushort4 y = ((const ushort4*)b)[i];
  ushort4 r;
  r.x = f2bf(bf2f(x.x) + bf2f(y.x));
  r.y = f2bf(bf2f(x.y) + bf2f(y.y));
  r.z = f2bf(bf2f(x.z) + bf2f(y.z));
  r.w = f2bf(bf2f(x.w) + bf2f(y.w));
  ((ushort4*)o)[i] = r;
}

// out = -(a + b) (f32, n4 = elems/4)
__global__ __launch_bounds__(256) void comb_out(const float* a, const float* b, float* o, int n4) {
  int i = blockIdx.x * 256 + threadIdx.x;
  if (i >= n4) return;
  float4 x = ((const float4*)a)[i];
  float4 y = ((const float4*)b)[i];
  ((float4*)o)[i] = make_float4(-(x.x + y.x), -(x.y + y.y), -(x.z + y.z), -(x.w + y.w));
}

// t[row] = sum_j KP[row][j]
__global__ __launch_bounds__(256) void rowsum_bf(const u16* KP, float* t, int width) {
  int w = threadIdx.x >> 6, lane = threadIdx.x & 63;
  int row = blockIdx.x * 4 + w;
  float s = 0.f;
  for (int k0 = lane * 8; k0 < width; k0 += 512) {
    bf16x8 mv = *(const bf16x8*)&KP[(size_t)row * width + k0];
    #pragma unroll
    for (int e = 0; e < 8; ++e) s += bf2f((u16)mv[e]);
  }
  #pragma unroll
  for (int off = 32; off > 0; off >>= 1) s += __shfl_down(s, off);
  if (lane == 0) t[row] = s;
}

// fused: u[row] = dot(C_row, t); D_hat[row][:] = 0.5*(1-u)/512 + 0.5*DF[row][:]
__global__ __launch_bounds__(256) void matvec_dhat(const float* Cm, const float* t,
                                                   const float* DF, float* out) {
  __shared__ float ts[2048];
  for (int i = threadIdx.x; i < 2048; i += 256) ts[i] = t[i];
  __syncthreads();
  int w = threadIdx.x >> 6, lane = threadIdx.x & 63;
  int row = blockIdx.x * 4 + w;
  float s = 0.f;
  for (int k0 = lane * 4; k0 < 2048; k0 += 256) {
    float4 c4 = *(const float4*)&Cm[(size_t)row * 2048 + k0];
    s += c4.x * ts[k0] + c4.y * ts[k0 + 1] + c4.z * ts[k0 + 2] + c4.w * ts[k0 + 3];
  }
  #pragma unroll
  for (int off = 32; off > 0; off >>= 1) s += __shfl_down(s, off);
  s = __shfl(s, 0);
  float coef = 0.5f * (1.0f - s) * (1.0f / 512.0f);
  int j = lane * 8;
  #pragma unroll
  for (int e = 0; e < 8; ++e)
    out[(size_t)row * 512 + j + e] = coef + 0.5f * DF[(size_t)row * 512 + j + e];
}

extern "C" void kernel_launch(void* const* d_in, const int* in_sizes, int n_in,
                              void* d_out, int out_size, void* d_ws, size_t ws_size,
                              hipStream_t stream) {
  (void)in_sizes; (void)n_in; (void)out_size; (void)ws_size;
  const float* Cf  = (const float*)d_in[0];  // [512][2048]
  const float* Af  = (const float*)d_in[1];  // [2048][2048]
  const float* AFf = (const float*)d_in[2];  // [2048][2048]
  const float* BFf = (const float*)d_in[3];  // [2048][512]
  const float* CFf = (const float*)d_in[4];  // [512][2048]
  const float* DFf = (const float*)d_in[5];  // [512][512]
  float* out = (float*)d_out;                // B_hat [2048][512] ++ D_hat [512][512]

  const size_t NN = 2048ull * 2048ull;
  const size_t SK = 512ull * 2048ull;
  char* ws = (char*)d_ws;
  u16* Mb   = (u16*)ws;            // M = A^T [2048][2048]
  u16* Nb   = Mb + NN;             // N = A_F [2048][2048]
  u16* NbT  = Nb + NN;             // N^T
  u16* KP   = NbT + NN;            // [P0|P1|P2|P3] [2048][2048]
  u16* Cb   = KP + NN;             // C [512][2048] (= P0^T)
  u16* P1T  = Cb + SK;             // P1^T
  u16* P2T  = P1T + SK;            // P2^T
  u16* BFT  = P2T + SK;            // B_F^T = e0^T
  u16* E1T  = BFT + SK;            // e1^T
  u16* E2T  = E1T + SK;            // e2^T
  u16* R1   = E2T + SK;            // r1 = C_F N [512][2048]
  u16* WB   = R1 + SK;             // [w0^T|w1^T|w2^T|w3^T] [512][2048]
  u16* WBp0 = WB + SK;             // split-K partials
  u16* WBp1 = WBp0 + SK;
  u16* CFb  = WBp1 + SK;           // C_F [512][2048]
  float* Vp0 = (float*)(CFb + SK); // G5 partial f32 [2048][512]
  float* Vp1 = Vp0 + 2048ull * 512;
  float* tv  = Vp1 + 2048ull * 512;

  auto mk = [](const u16* A, int lda, const u16* Bt, int ldb,
               u16* D, u16* Dt, float* Df, int ldd, int lddt,
               int M, int N, int K, float scale, int bm, int bn) {
    GemmDesc g; g.A = A; g.Bt = Bt; g.D = D; g.Dt = Dt; g.Df = Df;
    g.M = M; g.N = N; g.K = K; g.lda = lda; g.ldb = ldb; g.ldd = ldd; g.lddt = lddt;
    g.tn = N / bn; g.tiles = (M / bm) * (N / bn); g.scale = scale; return g;
  };

  // ---- conversions ----
  conv_all<<<1344, 256, 0, stream>>>(Af, AFf, Cf, BFf, CFf, Mb, Nb, NbT, Cb, KP, BFT, CFb);

  // ---- G1 (256): P1 = M@P0 (D->KP+512, Dt->P1T) | e1 = N@e0 (Dt->E1T) ----
  { GemmBatch gb{}; gb.nd = 2;
    gb.d[0] = mk(Mb, 2048, Cb, 2048, KP + 512, P1T, nullptr, 2048, 2048, 2048, 512, 2048, 1.f, 128, 64);
    gb.d[1] = mk(Nb, 2048, BFT, 2048, nullptr, E1T, nullptr, 0, 2048, 2048, 512, 2048, 1.f, 128, 64);
    gemm_db<128, 64><<<256, 256, 0, stream>>>(gb); }

  // ---- G2 (256): P2 = M@P1 (D->KP+1024, Dt->P2T) | r1 = C_F@N (D->R1) ----
  { GemmBatch gb{}; gb.nd = 2;
    gb.d[0] = mk(Mb, 2048, P1T, 2048, KP + 1024, P2T, nullptr, 2048, 2048, 2048, 512, 2048, 1.f, 128, 64);
    gb.d[1] = mk(CFb, 2048, NbT, 2048, R1, nullptr, nullptr, 2048, 0, 512, 2048, 2048, 1.f, 128, 64);
    gemm_db<128, 64><<<256, 256, 0, stream>>>(gb); }

  // ---- G3 (256): P3 = M@P2 (D->KP+1536) | e2 = N@e1 (Dt->E2T) ----
  { GemmBatch gb{}; gb.nd = 2;
    gb.d[0] = mk(Mb, 2048, P2T, 2048, KP + 1536, nullptr, nullptr, 2048, 0, 2048, 512, 2048, 1.f, 128, 64);
    gb.d[1] = mk(Nb, 2048, E1T, 2048, nullptr, E2T, nullptr, 0, 2048, 2048, 512, 2048, 1.f, 128, 64);
    gemm_db<128, 64><<<256, 256, 0, stream>>>(gb); }

  // ---- G4 (256): w_k split-K=2 -> bf16 partials; w0,w1 = C_F@{e0,e1}; w2,w3 = r1@{e1,e2} ----
  { GemmBatch gb{}; gb.nd = 8;
    const u16* As[4] = {CFb, CFb, R1, R1};
    const u16* Bs[4] = {BFT, E1T, E1T, E2T};
    for (int k = 0; k < 4; ++k)
      for (int h = 0; h < 2; ++h)
        gb.d[k * 2 + h] = mk(As[k] + h * 1024, 2048, Bs[k] + h * 1024, 2048,
                             nullptr, (h ? WBp1 : WBp0) + 512 * k, nullptr, 0, 2048,
                             512, 512, 1024, 1.f, 128, 64);
    gemm_db<128, 64><<<256, 256, 0, stream>>>(gb); }
  comb_wb<<<1024, 256, 0, stream>>>(WBp0, WBp1, WB, (512 * 2048) / 4);

  // ---- G5 (256): B_hat split-K=2: Vp_h = KP[:,h*1024:]@WB[:,h*1024:]^T (f32) ----
  { GemmBatch gb{}; gb.nd = 2;
    gb.d[0] = mk(KP, 2048, WB, 2048, nullptr, nullptr, Vp0, 512, 0, 2048, 512, 1024, 1.f, 128, 64);
    gb.d[1] = mk(KP + 1024, 2048, WB + 1024, 2048, nullptr, nullptr, Vp1, 512, 0, 2048, 512, 1024, 1.f, 128, 64);
    gemm_db<128, 64><<<256, 256, 0, stream>>>(gb); }
  comb_out<<<1024, 256, 0, stream>>>(Vp0, Vp1, out, (2048 * 512) / 4);

  // ---- D_hat: t = rowsum(KP) ; u = C t ; D_hat fused ----
  rowsum_bf<<<512, 256, 0, stream>>>(KP, tv, 2048);
  matvec_dhat<<<128, 256, 0, stream>>>(Cf, tv, DFf, out + 2048 * 512);
}

// Round 18
// 112.286 us; speedup vs baseline: 1.2952x; 1.0441x over previous
//
#include <hip/hip_runtime.h>

typedef unsigned char u8;
typedef __attribute__((ext_vector_type(4))) float f32x4;

#define AS1 __attribute__((address_space(1)))
#define AS3 __attribute__((address_space(3)))

__device__ __forceinline__ void gload16(const void* g, void* l) {
  __builtin_amdgcn_global_load_lds((const AS1 unsigned int*)g, (AS3 unsigned int*)l, 16, 0, 0);
}
// pack 4 floats -> 4 e4m3 bytes (RNE, saturating)
__device__ __forceinline__ unsigned int f2e4x4(float a, float b, float c, float d) {
  int v = __builtin_amdgcn_cvt_pk_fp8_f32(a, b, 0, false);
  v = __builtin_amdgcn_cvt_pk_fp8_f32(c, d, v, true);
  return (unsigned int)v;
}
__device__ __forceinline__ u8 f2e4(float a) {
  return (u8)(__builtin_amdgcn_cvt_pk_fp8_f32(a, a, 0, false) & 0xff);
}
template<int SEL>
__device__ __forceinline__ float e42f(unsigned int w) {
  return __builtin_amdgcn_cvt_f32_fp8(w, SEL);  // SEL must be a literal constant
}

struct GemmDesc {
  const u8* A;       // [M][K] fp8 (32x scaled), row stride lda
  const u8* Bt;      // [N][K] fp8 (32x scaled), row stride ldb
  u8* D;             // optional fp8 out, row stride ldd
  u8* Dt;            // optional fp8 transposed out [N][M], row stride lddt
  float* Df;         // optional f32 out, row stride ldd
  int M, N, K, lda, ldb, ldd, lddt, tn, tiles;
  float scale;       // applied to raw acc (acc = 1024 * true product)
};
struct GemmBatch { GemmDesc d[8]; int nd; };

template<int BM, int BN, int FM, int FN>
__device__ __forceinline__ void epilogue(const GemmDesc& d, f32x4 (&acc)[FM][FN],
                                         int m0, int n0, int wm, int wn, int lane) {
  const int r4 = (lane >> 4) << 2;
  const int cc = lane & 15;
  #pragma unroll
  for (int i = 0; i < FM; ++i) {
    #pragma unroll
    for (int j = 0; j < FN; ++j) {
      const int row0 = m0 + wm * (BM / 2) + i * 16 + r4;
      const int col = n0 + wn * (BN / 2) + j * 16 + cc;
      float v[4];
      #pragma unroll
      for (int q = 0; q < 4; ++q) v[q] = acc[i][j][q] * d.scale;
      if (d.D) {
        #pragma unroll
        for (int q = 0; q < 4; ++q) d.D[(size_t)(row0 + q) * d.ldd + col] = f2e4(v[q]);
      }
      if (d.Df) {
        #pragma unroll
        for (int q = 0; q < 4; ++q) d.Df[(size_t)(row0 + q) * d.ldd + col] = v[q];
      }
      if (d.Dt) {
        unsigned int pk = f2e4x4(v[0], v[1], v[2], v[3]);
        *(unsigned int*)&d.Dt[(size_t)col * d.lddt + row0] = pk;
      }
    }
  }
}

// ---------- fp8 BK=128, 3-buffer, one-barrier-per-K-step pipeline ----------
// LDS row = 64 bytes (64 fp8). Swizzle at 16B granularity: LDS[r][c16] holds
// global[r][c16 ^ ((r&3)<<4)] — gload16-compatible both sides (rule 21).
// Residual 4-way ds_read conflict (1.58x) is off the critical path (staging-bound).
template<int BM, int BN>
__global__ __launch_bounds__(256) void gemm_f8(GemmBatch b) {
  const int nwg = gridDim.x;  // multiple of 8
  int t = ((blockIdx.x & 7) * (nwg >> 3)) + (blockIdx.x >> 3);
  int di = 0;
  while (di + 1 < b.nd && t >= b.d[di].tiles) { t -= b.d[di].tiles; ++di; }
  const GemmDesc d = b.d[di];
  const int tm = t / d.tn, tnn = t - tm * d.tn;
  const int m0 = tm * BM, n0 = tnn * BN;
  const int lane = threadIdx.x & 63;
  const int w = threadIdx.x >> 6;
  const int wm = w >> 1, wn = w & 1;
  constexpr int FM = BM / 32, FN = BN / 32;
  constexpr int HB = (BM + BN) * 64;       // bytes per 64-col half
  constexpr int L = 2 * (BM + BN) / 64;    // gload16 per wave per 128-K tile
  __shared__ __align__(16) u8 lds[6 * HB];  // 3 buffers x 2 halves
  f32x4 acc[FM][FN];
  #pragma unroll
  for (int i = 0; i < FM; ++i)
    #pragma unroll
    for (int j = 0; j < FN; ++j)
      acc[i][j] = (f32x4){0.f, 0.f, 0.f, 0.f};
  const int srow = lane >> 2;                               // 16 rows per gload16
  const int scolz = ((lane & 3) << 4) ^ ((srow & 3) << 4);  // pre-swizzled src col
  const int rsw = (lane & 3) << 4;                          // read-side XOR
  const int koff = (lane >> 4) << 3;
  const int nt = d.K / 128;

  auto stagef = [&](int tt, int buf) {
    #pragma unroll
    for (int h = 0; h < 2; ++h) {
      const int k0 = tt * 128 + h * 64;
      u8* base = &lds[(buf * 2 + h) * HB];
      #pragma unroll
      for (int c = w; c < BM / 16; c += 4)
        gload16(d.A + (size_t)(m0 + c * 16 + srow) * d.lda + k0 + scolz, base + c * 1024);
      #pragma unroll
      for (int c = w; c < BN / 16; c += 4)
        gload16(d.Bt + (size_t)(n0 + c * 16 + srow) * d.ldb + k0 + scolz, base + BM * 64 + c * 1024);
    }
  };

  stagef(0, 0);
  stagef(1, 1);
  __builtin_amdgcn_sched_barrier(0);
  asm volatile("s_waitcnt vmcnt(%0)" :: "n"(L));  // tile0 landed (ours)
  __builtin_amdgcn_s_barrier();
  __builtin_amdgcn_sched_barrier(0);

  int cur = 0;
  for (int tt = 0; tt < nt; ++tt) {
    #pragma unroll
    for (int h = 0; h < 2; ++h) {
      const u8* base = &lds[(cur * 2 + h) * HB];
      #pragma unroll
      for (int kk = 0; kk < 64; kk += 32) {
        const int cb = (kk + koff) ^ rsw;  // swizzled byte col (8B aligned)
        long af[FM], bfr[FN];
        #pragma unroll
        for (int i = 0; i < FM; ++i)
          af[i] = *(const long*)&base[(wm * (BM / 2) + i * 16 + (lane & 15)) * 64 + cb];
        #pragma unroll
        for (int j = 0; j < FN; ++j)
          bfr[j] = *(const long*)&base[BM * 64 + (wn * (BN / 2) + j * 16 + (lane & 15)) * 64 + cb];
        #pragma unroll
        for (int i = 0; i < FM; ++i)
          #pragma unroll
          for (int j = 0; j < FN; ++j)
            acc[i][j] = __builtin_amdgcn_mfma_f32_16x16x32_fp8_fp8(af[i], bfr[j], acc[i][j], 0, 0, 0);
      }
    }
    if (tt + 1 < nt) {
      __builtin_amdgcn_sched_barrier(0);
      if (tt + 2 < nt) {
        int nb = cur + 2; if (nb >= 3) nb -= 3;
        stagef(tt + 2, nb);                       // loads fly across the barrier
        __builtin_amdgcn_sched_barrier(0);
        asm volatile("s_waitcnt vmcnt(%0)" :: "n"(L));
      } else {
        asm volatile("s_waitcnt vmcnt(0)");
      }
      __builtin_amdgcn_s_barrier();      // single barrier per K-step
      __builtin_amdgcn_sched_barrier(0);
    }
    cur = (cur == 2) ? 0 : cur + 1;
  }
  epilogue<BM, BN, FM, FN>(d, acc, m0, n0, wm, wn, lane);
}

// ---------- fused conversions: f32 -> fp8 (x32 scale), straight and/or transposed ----------
__global__ __launch_bounds__(256) void conv_all(const float* Af, const float* AFf,
                                                const float* Cf, const float* BFf,
                                                const float* CFf,
                                                u8* Mb, u8* Nb, u8* NbT, u8* Cb,
                                                u8* KP, u8* BFT, u8* CFb) {
  __shared__ float tile[64][65];
  const int tid = threadIdx.x;
  const int lr = tid >> 6, lc = tid & 63;
  for (int u = blockIdx.x; u < 2816; u += 1408) {
    __syncthreads();
    const float* src = nullptr;
    u8 *outS = nullptr, *outT = nullptr;
    int r0, c0, C = 2048;
    const int ldt = 2048;
    if (u < 1024) {
      src = Af; outT = Mb; r0 = (u >> 5) << 6; c0 = (u & 31) << 6;
    } else if (u < 2048) {
      int bb = u - 1024; src = AFf; outS = Nb; outT = NbT; r0 = (bb >> 5) << 6; c0 = (bb & 31) << 6;
    } else if (u < 2304) {
      int bb = u - 2048; src = Cf; outS = Cb; outT = KP; r0 = (bb >> 5) << 6; c0 = (bb & 31) << 6;
    } else if (u < 2560) {
      int bb = u - 2304; src = BFf; outT = BFT; C = 512; r0 = (bb >> 3) << 6; c0 = (bb & 7) << 6;
    } else {
      // CFb = 32*C_F straight, grid-stride over 512x2048
      const int n4 = (512 * 2048) / 4;
      for (int i = (u - 2560) * 256 + tid; i < n4; i += 256 * 256) {
        float4 f = ((const float4*)CFf)[i];
        ((unsigned int*)CFb)[i] = f2e4x4(32.f * f.x, 32.f * f.y, 32.f * f.z, 32.f * f.w);
      }
      continue;
    }
    #pragma unroll
    for (int p = 0; p < 16; ++p) {
      int r = p * 4 + lr;
      tile[r][lc] = 32.f * src[(size_t)(r0 + r) * C + c0 + lc];
    }
    __syncthreads();
    const int orow = tid >> 4, oc4 = (tid & 15) << 2;
    if (outS) {
      #pragma unroll
      for (int q = 0; q < 4; ++q) {
        int rr = q * 16 + orow;
        unsigned int pk = f2e4x4(tile[rr][oc4], tile[rr][oc4 + 1], tile[rr][oc4 + 2], tile[rr][oc4 + 3]);
        *(unsigned int*)&outS[(size_t)(r0 + rr) * C + c0 + oc4] = pk;
      }
    }
    if (outT) {
      #pragma unroll
      for (int q = 0; q < 4; ++q) {
        int rr = q * 16 + orow;  // output row = source col c0+rr
        unsigned int pk = f2e4x4(tile[oc4][rr], tile[oc4 + 1][rr], tile[oc4 + 2][rr], tile[oc4 + 3][rr]);
        *(unsigned int*)&outT[(size_t)(c0 + rr) * ldt + r0 + oc4] = pk;
      }
    }
  }
}

// WB = WBp0 + WBp1 (fp8, n4 = bytes/4)
__global__ __launch_bounds__(256) void comb_wb(const u8* a, const u8* b, u8* o, int n4) {
  int i = blockIdx.x * 256 + threadIdx.x;
  if (i >= n4) return;
  unsigned int x = ((const unsigned int*)a)[i];
  unsigned int y = ((const unsigned int*)b)[i];
  ((unsigned int*)o)[i] = f2e4x4(e42f<0>(x) + e42f<0>(y), e42f<1>(x) + e42f<1>(y),
                                 e42f<2>(x) + e42f<2>(y), e42f<3>(x) + e42f<3>(y));
}

// out = -(a + b) (f32)
__global__ __launch_bounds__(256) void comb_out(const float* a, const float* b, float* o, int n4) {
  int i = blockIdx.x * 256 + threadIdx.x;
  if (i >= n4) return;
  float4 x = ((const float4*)a)[i];
  float4 y = ((const float4*)b)[i];
  ((float4*)o)[i] = make_float4(-(x.x + y.x), -(x.y + y.y), -(x.z + y.z), -(x.w + y.w));
}

// t[row] = (1/32) * sum_j KP[row][j] (fp8 32x-scaled)
__global__ __launch_bounds__(256) void rowsum_f8(const u8* KP, float* t, int width) {
  int w = threadIdx.x >> 6, lane = threadIdx.x & 63;
  int row = blockIdx.x * 4 + w;
  float s = 0.f;
  for (int k0 = lane * 8; k0 < width; k0 += 512) {
    uint2 mv = *(const uint2*)&KP[(size_t)row * width + k0];
    s += e42f<0>(mv.x) + e42f<1>(mv.x) + e42f<2>(mv.x) + e42f<3>(mv.x);
    s += e42f<0>(mv.y) + e42f<1>(mv.y) + e42f<2>(mv.y) + e42f<3>(mv.y);
  }
  #pragma unroll
  for (int off = 32; off > 0; off >>= 1) s += __shfl_down(s, off);
  if (lane == 0) t[row] = s * (1.f / 32.f);
}

// fused: u[row] = dot(C_row, t); D_hat[row][:] = 0.5*(1-u)/512 + 0.5*DF[row][:]
__global__ __launch_bounds__(256) void matvec_dhat(const float* Cm, const float* t,
                                                   const float* DF, float* out) {
  __shared__ float ts[2048];
  for (int i = threadIdx.x; i < 2048; i += 256) ts[i] = t[i];
  __syncthreads();
  int w = threadIdx.x >> 6, lane = threadIdx.x & 63;
  int row = blockIdx.x * 4 + w;
  float s = 0.f;
  for (int k0 = lane * 4; k0 < 2048; k0 += 256) {
    float4 c4 = *(const float4*)&Cm[(size_t)row * 2048 + k0];
    s += c4.x * ts[k0] + c4.y * ts[k0 + 1] + c4.z * ts[k0 + 2] + c4.w * ts[k0 + 3];
  }
  #pragma unroll
  for (int off = 32; off > 0; off >>= 1) s += __shfl_down(s, off);
  s = __shfl(s, 0);
  float coef = 0.5f * (1.0f - s) * (1.0f / 512.0f);
  int j = lane * 8;
  #pragma unroll
  for (int e = 0; e < 8; ++e)
    out[(size_t)row * 512 + j + e] = coef + 0.5f * DF[(size_t)row * 512 + j + e];
}

extern "C" void kernel_launch(void* const* d_in, const int* in_sizes, int n_in,
                              void* d_out, int out_size, void* d_ws, size_t ws_size,
                              hipStream_t stream) {
  (void)in_sizes; (void)n_in; (void)out_size; (void)ws_size;
  const float* Cf  = (const float*)d_in[0];  // [512][2048]
  const float* Af  = (const float*)d_in[1];  // [2048][2048]
  const float* AFf = (const float*)d_in[2];  // [2048][2048]
  const float* BFf = (const float*)d_in[3];  // [2048][512]
  const float* CFf = (const float*)d_in[4];  // [512][2048]
  const float* DFf = (const float*)d_in[5];  // [512][512]
  float* out = (float*)d_out;                // B_hat [2048][512] ++ D_hat [512][512]

  const size_t NN = 2048ull * 2048ull;       // bytes (fp8)
  const size_t SK = 512ull * 2048ull;
  char* ws = (char*)d_ws;
  u8* Mb   = (u8*)ws;              // 32*M = 32*A^T [2048][2048] fp8
  u8* Nb   = Mb + NN;              // 32*N
  u8* NbT  = Nb + NN;              // 32*N^T
  u8* KP   = NbT + NN;             // 32*[P0|P1|P2|P3] [2048][2048]
  u8* Cb   = KP + NN;              // 32*C [512][2048] (= 32*P0^T)
  u8* P1T  = Cb + SK;              // 32*P1^T
  u8* P2T  = P1T + SK;             // 32*P2^T
  u8* BFT  = P2T + SK;             // 32*B_F^T = 32*e0^T
  u8* E1T  = BFT + SK;             // 32*e1^T
  u8* E2T  = E1T + SK;             // 32*e2^T
  u8* R1   = E2T + SK;             // 32*r1 = 32*C_F N [512][2048]
  u8* WB   = R1 + SK;              // 32*[w0^T|w1^T|w2^T|w3^T]
  u8* WBp0 = WB + SK;              // split-K partials
  u8* WBp1 = WBp0 + SK;
  u8* CFb  = WBp1 + SK;            // 32*C_F [512][2048]
  float* Vp0 = (float*)(CFb + SK); // G5 partial f32 [2048][512]
  float* Vp1 = Vp0 + 2048ull * 512;
  float* tv  = Vp1 + 2048ull * 512;

  auto mk = [](const u8* A, int lda, const u8* Bt, int ldb,
               u8* D, u8* Dt, float* Df, int ldd, int lddt,
               int M, int N, int K, float scale, int bm, int bn) {
    GemmDesc g; g.A = A; g.Bt = Bt; g.D = D; g.Dt = Dt; g.Df = Df;
    g.M = M; g.N = N; g.K = K; g.lda = lda; g.ldb = ldb; g.ldd = ldd; g.lddt = lddt;
    g.tn = N / bn; g.tiles = (M / bm) * (N / bn); g.scale = scale; return g;
  };
  const float S32 = 1.f / 32.f;     // rescale 1024x acc -> 32x value
  const float SF  = 1.f / 1024.f;   // rescale to true value

  conv_all<<<1408, 256, 0, stream>>>(Af, AFf, Cf, BFf, CFf, Mb, Nb, NbT, Cb, KP, BFT, CFb);

  // ---- G1 (256): P1 = M@P0 (D->KP+512, Dt->P1T) | e1 = N@e0 (Dt->E1T) ----
  { GemmBatch gb{}; gb.nd = 2;
    gb.d[0] = mk(Mb, 2048, Cb, 2048, KP + 512, P1T, nullptr, 2048, 2048, 2048, 512, 2048, S32, 128, 64);
    gb.d[1] = mk(Nb, 2048, BFT, 2048, nullptr, E1T, nullptr, 0, 2048, 2048, 512, 2048, S32, 128, 64);
    gemm_f8<128, 64><<<256, 256, 0, stream>>>(gb); }

  // ---- G2 (256): P2 = M@P1 (D->KP+1024, Dt->P2T) | r1 = C_F@N (D->R1) ----
  { GemmBatch gb{}; gb.nd = 2;
    gb.d[0] = mk(Mb, 2048, P1T, 2048, KP + 1024, P2T, nullptr, 2048, 2048, 2048, 512, 2048, S32, 128, 64);
    gb.d[1] = mk(CFb, 2048, NbT, 2048, R1, nullptr, nullptr, 2048, 0, 512, 2048, 2048, S32, 128, 64);
    gemm_f8<128, 64><<<256, 256, 0, stream>>>(gb); }

  // ---- G3 (256): P3 = M@P2 (D->KP+1536) | e2 = N@e1 (Dt->E2T) ----
  { GemmBatch gb{}; gb.nd = 2;
    gb.d[0] = mk(Mb, 2048, P2T, 2048, KP + 1536, nullptr, nullptr, 2048, 0, 2048, 512, 2048, S32, 128, 64);
    gb.d[1] = mk(Nb, 2048, E1T, 2048, nullptr, E2T, nullptr, 0, 2048, 2048, 512, 2048, S32, 128, 64);
    gemm_f8<128, 64><<<256, 256, 0, stream>>>(gb); }

  // ---- G4 (256): w_k split-K=2 -> fp8 partials; w0,w1 = C_F@{e0,e1}; w2,w3 = r1@{e1,e2} ----
  { GemmBatch gb{}; gb.nd = 8;
    const u8* As[4] = {CFb, CFb, R1, R1};
    const u8* Bs[4] = {BFT, E1T, E1T, E2T};
    for (int k = 0; k < 4; ++k)
      for (int h = 0; h < 2; ++h)
        gb.d[k * 2 + h] = mk(As[k] + h * 1024, 2048, Bs[k] + h * 1024, 2048,
                             nullptr, (h ? WBp1 : WBp0) + 512 * k, nullptr, 0, 2048,
                             512, 512, 1024, S32, 128, 64);
    gemm_f8<128, 64><<<256, 256, 0, stream>>>(gb); }
  comb_wb<<<1024, 256, 0, stream>>>(WBp0, WBp1, WB, (512 * 2048) / 4);

  // ---- G5 (256): B_hat split-K=2: Vp_h = KP[:,h*1024:]@WB[:,h*1024:]^T (f32, true scale) ----
  { GemmBatch gb{}; gb.nd = 2;
    gb.d[0] = mk(KP, 2048, WB, 2048, nullptr, nullptr, Vp0, 512, 0, 2048, 512, 1024, SF, 128, 64);
    gb.d[1] = mk(KP + 1024, 2048, WB + 1024, 2048, nullptr, nullptr, Vp1, 512, 0, 2048, 512, 1024, SF, 128, 64);
    gemm_f8<128, 64><<<256, 256, 0, stream>>>(gb); }
  comb_out<<<1024, 256, 0, stream>>>(Vp0, Vp1, out, (2048 * 512) / 4);

  // ---- D_hat: t = rowsum(KP)/32 ; u = C t ; D_hat fused ----
  rowsum_f8<<<512, 256, 0, stream>>>(KP, tv, 2048);
  matvec_dhat<<<128, 256, 0, stream>>>(Cf, tv, DFf, out + 2048 * 512);
}